// Round 3
// baseline (786.842 us; speedup 1.0000x reference)
//
#include <hip/hip_runtime.h>
#include <hip/hip_fp16.h>

#define N_NODES 100000
#define N_EDGES 3200000
#define F 256

#define BM 64
#define BN 256
#define BK 32

#define MAX_DEG 80                         // P(Poisson(32) > 80) ~ 4e-12 over all nodes
#define INIT_NB ((N_NODES + 255) / 256)    // 391 blocks
#define EDGE_NB4 (N_EDGES / 1024)          // 3125 blocks, 4 edges/thread, exact

typedef __attribute__((ext_vector_type(8))) short short8;
typedef __attribute__((ext_vector_type(4))) float f32x4;

__device__ inline unsigned short f2bf(float f) {
    unsigned int u = __float_as_uint(f);
    unsigned int r = (u + 0x7fffu + ((u >> 16) & 1u)) >> 16;
    return (unsigned short)r;
}

__device__ inline float bf2f(unsigned short b) {
    return __uint_as_float(((unsigned int)b) << 16);
}

// Pack an edge record into 4B: src (17 bits, <131072) | f16(val) (15 bits,
// val in [0,1) so sign bit is always 0 and exponent never saturates).
__device__ inline unsigned int pack_rec(int src, float val) {
    __half h = __float2half(val);
    unsigned short hb = *reinterpret_cast<unsigned short*>(&h);
    return ((unsigned int)src << 15) | (unsigned int)hb;
}

__device__ inline int rec_src(unsigned int p) { return (int)(p >> 15); }

__device__ inline float rec_val(unsigned int p) {
    unsigned short hb = (unsigned short)(p & 0x7FFFu);
    __half h = *reinterpret_cast<__half*>(&hb);
    return __half2float(h);
}

// ---------------------------------------------------------------------------
// Init: zero the degree counters AND build Wt[n][k] = bf16(W[k][n]).
// One dispatch replaces memset + wt_kernel.
// ---------------------------------------------------------------------------
__global__ __launch_bounds__(256)
void init_kernel(const float* __restrict__ W, unsigned short* __restrict__ Wt,
                 int* __restrict__ counts) {
    const int idx = blockIdx.x * 256 + threadIdx.x;
    if (idx < N_NODES) counts[idx] = 0;
    if (idx < 256 * 256) {
        const int n = idx >> 8;
        const int k = idx & 255;
        Wt[n * 256 + k] = f2bf(W[k * 256 + n]);
    }
}

// ---------------------------------------------------------------------------
// Bucketed CSR build in ONE pass: rank = atomicAdd(counts[dst]), record placed
// at recs[dst*MAX_DEG + rank]. Replaces rank_hist + 3 scan kernels + fill:
// one scattered pass over the edges instead of two, no rank array, no scan.
// 4 edges/thread, vector loads. Overflow guard (never taken for this graph)
// prevents memory corruption.
// ---------------------------------------------------------------------------
__global__ __launch_bounds__(256)
void bucket_fill_kernel(const int* __restrict__ src, const int* __restrict__ dst,
                        const float* __restrict__ val,
                        int* __restrict__ counts, unsigned int* __restrict__ recs) {
    const int e0 = (blockIdx.x * 256 + threadIdx.x) * 4;
    const int4   s = *(const int4*)(src + e0);
    const int4   d = *(const int4*)(dst + e0);
    const float4 v = *(const float4*)(val + e0);
    const int r0 = atomicAdd(&counts[d.x], 1);
    const int r1 = atomicAdd(&counts[d.y], 1);
    const int r2 = atomicAdd(&counts[d.z], 1);
    const int r3 = atomicAdd(&counts[d.w], 1);
    if (r0 < MAX_DEG) recs[d.x * MAX_DEG + r0] = pack_rec(s.x, v.x);
    if (r1 < MAX_DEG) recs[d.y * MAX_DEG + r1] = pack_rec(s.y, v.y);
    if (r2 < MAX_DEG) recs[d.z * MAX_DEG + r2] = pack_rec(s.z, v.z);
    if (r3 < MAX_DEG) recs[d.w * MAX_DEG + r3] = pack_rec(s.w, v.w);
}

// ---------------------------------------------------------------------------
// GEMM: out[n, 0:256] = input[n, :] @ W  (fp32) + compact bf16 copy ftb[n][256].
// BM=64: 1563 blocks (3/CU). MFMA operands SWAPPED (mfma(b,a)) -> transposed
// C-fragment: lane holds 4 consecutive columns of one row -> float4 stores.
// ---------------------------------------------------------------------------
__global__ __launch_bounds__(256, 3)
void gemm_kernel(const float* __restrict__ A,
                 const unsigned short* __restrict__ Wt,
                 float* __restrict__ out,
                 unsigned short* __restrict__ ftb)
{
    __shared__ unsigned short As[BM * BK];   // 4 KB
    __shared__ unsigned short Bs[BN * BK];   // 16 KB

    const int tid   = threadIdx.x;
    const int lane  = tid & 63;
    const int wave  = tid >> 6;
    const int waveM = wave >> 1;             // 0..1 : 32-row half
    const int waveN = wave & 1;              // 0..1 : 128-col half
    const int rowBase = blockIdx.x * BM;

    f32x4 acc[2][8];
#pragma unroll
    for (int i = 0; i < 2; i++)
#pragma unroll
        for (int j = 0; j < 8; j++) acc[i][j] = (f32x4)0.0f;

    const int sr = tid >> 2;        // 0..63
    const int sk = (tid & 3) * 8;   // 0,8,16,24
    const int quad = lane >> 4;
    const int l16  = lane & 15;

    for (int kt = 0; kt < 8; kt++) {
        const int k0 = kt * BK;
        // A tile: 64 rows x 32 cols, fp32 -> bf16 convert
        {
            const int grow = rowBase + sr;
            short8 av;
            if (grow < N_NODES) {
                const float4* pa = (const float4*)(A + (size_t)grow * 256 + k0 + sk);
                float4 f0 = pa[0];
                float4 f1 = pa[1];
                av[0] = (short)f2bf(f0.x); av[1] = (short)f2bf(f0.y);
                av[2] = (short)f2bf(f0.z); av[3] = (short)f2bf(f0.w);
                av[4] = (short)f2bf(f1.x); av[5] = (short)f2bf(f1.y);
                av[6] = (short)f2bf(f1.z); av[7] = (short)f2bf(f1.w);
            } else {
                av = (short8)0;
            }
            *(short8*)(&As[sr * BK + sk]) = av;
        }
        // B tile: 256 rows (output cols) x 32
#pragma unroll
        for (int p = 0; p < 4; p++) {
            const int r = p * 64 + sr;
            const uint4 wv = *(const uint4*)(Wt + (size_t)r * 256 + k0 + sk);
            *(uint4*)(&Bs[r * BK + sk]) = wv;
        }
        __syncthreads();

        short8 af[2], bfr[8];
#pragma unroll
        for (int i = 0; i < 2; i++)
            af[i] = *(const short8*)(&As[(waveM * 32 + i * 16 + l16) * BK + quad * 8]);
#pragma unroll
        for (int j = 0; j < 8; j++)
            bfr[j] = *(const short8*)(&Bs[(waveN * 128 + j * 16 + l16) * BK + quad * 8]);
#pragma unroll
        for (int i = 0; i < 2; i++)
#pragma unroll
            for (int j = 0; j < 8; j++)
                acc[i][j] = __builtin_amdgcn_mfma_f32_16x16x32_bf16(
                    bfr[j], af[i], acc[i][j], 0, 0, 0);   // swapped -> C^T fragment
        __syncthreads();
    }

    // Epilogue: lane holds out[row][col..col+3], row = ..+l16, col = ..+quad*4
#pragma unroll
    for (int i = 0; i < 2; i++) {
        const int row = rowBase + waveM * 32 + i * 16 + l16;
        if (row < N_NODES) {
#pragma unroll
            for (int j = 0; j < 8; j++) {
                const int col = waveN * 128 + j * 16 + quad * 4;
                f32x4 v = acc[i][j];
                *(f32x4*)(out + (size_t)row * 512 + col) = v;
                unsigned int p0 = ((unsigned int)f2bf(v[1]) << 16) | f2bf(v[0]);
                unsigned int p1 = ((unsigned int)f2bf(v[3]) << 16) | f2bf(v[2]);
                *(uint2*)(ftb + (size_t)row * 256 + col) = make_uint2(p0, p1);
            }
        }
    }
}

// ---------------------------------------------------------------------------
// Gather: one wave per dst node. out[n, 256:512] = sum_e val_e * ftb[src_e]
// Reads the fixed-stride bucket row (len = counts[n], base = n*MAX_DEG).
// 8-edge unroll + record prefetch. Random row reads at the ~3.5 TB/s
// random-access ceiling (established rounds 0-2).
// ---------------------------------------------------------------------------
__global__ __launch_bounds__(256)
void gather_kernel(const int* __restrict__ counts,
                   const unsigned int* __restrict__ recs,
                   const unsigned short* __restrict__ ftb,
                   float* __restrict__ out)
{
    const int n = blockIdx.x * 4 + (threadIdx.x >> 6);
    if (n >= N_NODES) return;
    const int lane = threadIdx.x & 63;

    int len = counts[n];
    if (len > MAX_DEG) len = MAX_DEG;
    const unsigned int* rp = recs + (size_t)n * MAX_DEG;

    float ax = 0.f, ay = 0.f, az = 0.f, aw = 0.f;

    int e = 0;

    if (e + 7 < len) {
        unsigned int r[8];
#pragma unroll
        for (int q = 0; q < 8; q++) r[q] = rp[e + q];
        while (true) {
            const int en = e + 8;
            const bool moreN = (en + 7 < len);
            unsigned int rn[8];
            if (moreN) {
#pragma unroll
                for (int q = 0; q < 8; q++) rn[q] = rp[en + q];
            }
            ushort4 u[8];
#pragma unroll
            for (int q = 0; q < 8; q++)
                u[q] = *(const ushort4*)(ftb + (size_t)rec_src(r[q]) * 256 + lane * 4);
#pragma unroll
            for (int q = 0; q < 8; q++) {
                const float v = rec_val(r[q]);
                ax += v * bf2f(u[q].x); ay += v * bf2f(u[q].y);
                az += v * bf2f(u[q].z); aw += v * bf2f(u[q].w);
            }
            e = en;
            if (!moreN) break;
#pragma unroll
            for (int q = 0; q < 8; q++) r[q] = rn[q];
        }
    }

    for (; e + 3 < len; e += 4) {
        unsigned int r0 = rp[e];
        unsigned int r1 = rp[e + 1];
        unsigned int r2 = rp[e + 2];
        unsigned int r3 = rp[e + 3];
        ushort4 u0 = *(const ushort4*)(ftb + (size_t)rec_src(r0) * 256 + lane * 4);
        ushort4 u1 = *(const ushort4*)(ftb + (size_t)rec_src(r1) * 256 + lane * 4);
        ushort4 u2 = *(const ushort4*)(ftb + (size_t)rec_src(r2) * 256 + lane * 4);
        ushort4 u3 = *(const ushort4*)(ftb + (size_t)rec_src(r3) * 256 + lane * 4);
        const float v0 = rec_val(r0);
        const float v1 = rec_val(r1);
        const float v2 = rec_val(r2);
        const float v3 = rec_val(r3);
        ax += v0 * bf2f(u0.x); ay += v0 * bf2f(u0.y);
        az += v0 * bf2f(u0.z); aw += v0 * bf2f(u0.w);
        ax += v1 * bf2f(u1.x); ay += v1 * bf2f(u1.y);
        az += v1 * bf2f(u1.z); aw += v1 * bf2f(u1.w);
        ax += v2 * bf2f(u2.x); ay += v2 * bf2f(u2.y);
        az += v2 * bf2f(u2.z); aw += v2 * bf2f(u2.w);
        ax += v3 * bf2f(u3.x); ay += v3 * bf2f(u3.y);
        az += v3 * bf2f(u3.z); aw += v3 * bf2f(u3.w);
    }
    for (; e < len; e++) {
        unsigned int r0 = rp[e];
        ushort4 u0 = *(const ushort4*)(ftb + (size_t)rec_src(r0) * 256 + lane * 4);
        const float v0 = rec_val(r0);
        ax += v0 * bf2f(u0.x); ay += v0 * bf2f(u0.y);
        az += v0 * bf2f(u0.z); aw += v0 * bf2f(u0.w);
    }

    float4 res = make_float4(ax, ay, az, aw);
    *(float4*)(out + (size_t)n * 512 + 256 + lane * 4) = res;
}

// ---------------------------------------------------------------------------
extern "C" void kernel_launch(void* const* d_in, const int* in_sizes, int n_in,
                              void* d_out, int out_size, void* d_ws, size_t ws_size,
                              hipStream_t stream)
{
    const float* input = (const float*)d_in[0];
    const int*   esrc  = (const int*)d_in[1];
    const int*   edst  = (const int*)d_in[2];
    const float* eval  = (const float*)d_in[3];
    const float* W     = (const float*)d_in[4];
    float* out = (float*)d_out;

    char* ws = (char*)d_ws;
    unsigned short* Wt  = (unsigned short*)(ws);                 // 131072 B
    int* counts         = (int*)(ws + 131072);                   // 400000 B
    unsigned int* recs  = (unsigned int*)(ws + 532480);          // 32.0 MB (100000*80*4)
    unsigned short* ftb = (unsigned short*)(ws + 32532480);      // 51.2 MB
    // total: 83.73 MB (< 84.1 MB used by the previously-passing version)

    init_kernel<<<INIT_NB, 256, 0, stream>>>(W, Wt, counts);
    bucket_fill_kernel<<<EDGE_NB4, 256, 0, stream>>>(esrc, edst, eval, counts, recs);

    dim3 g((N_NODES + BM - 1) / BM);
    gemm_kernel<<<g, 256, 0, stream>>>(input, Wt, out, ftb);

    gather_kernel<<<(N_NODES + 3) / 4, 256, 0, stream>>>(counts, recs, ftb, out);
}

// Round 4
// 618.403 us; speedup vs baseline: 1.2724x; 1.2724x over previous
//
#include <hip/hip_runtime.h>
#include <hip/hip_fp16.h>

#define N_NODES 100000
#define N_EDGES 3200000
#define F 256

#define BM 64
#define BN 256
#define BK 32

#define MAX_DEG 80                         // P(Poisson(32) > 80) ~ 4e-12 over all nodes
#define INIT_NB ((N_NODES + 255) / 256)    // 391 blocks
#define EDGE_NB4 (N_EDGES / 1024)          // 3125 bucket blocks, 4 edges/thread, exact
#define GEMM_NB ((N_NODES + BM - 1) / BM)  // 1563 gemm blocks
#define FUSED_NB (GEMM_NB + EDGE_NB4)      // 4688 = 1563*3 + 4687%3==1 -> mapping exact

typedef __attribute__((ext_vector_type(8))) short short8;
typedef __attribute__((ext_vector_type(4))) float f32x4;

__device__ inline unsigned short f2bf(float f) {
    unsigned int u = __float_as_uint(f);
    unsigned int r = (u + 0x7fffu + ((u >> 16) & 1u)) >> 16;
    return (unsigned short)r;
}

__device__ inline float bf2f(unsigned short b) {
    return __uint_as_float(((unsigned int)b) << 16);
}

// Pack an edge record into 4B: src (17 bits, <131072) | f16(val) (15 bits,
// val in [0,1) so sign bit is always 0 and exponent never saturates).
__device__ inline unsigned int pack_rec(int src, float val) {
    __half h = __float2half(val);
    unsigned short hb = *reinterpret_cast<unsigned short*>(&h);
    return ((unsigned int)src << 15) | (unsigned int)hb;
}

__device__ inline int rec_src(unsigned int p) { return (int)(p >> 15); }

__device__ inline float rec_val(unsigned int p) {
    unsigned short hb = (unsigned short)(p & 0x7FFFu);
    __half h = *reinterpret_cast<__half*>(&hb);
    return __half2float(h);
}

// ---------------------------------------------------------------------------
// Init: zero the degree counters AND build Wt[n][k] = bf16(W[k][n]).
// ---------------------------------------------------------------------------
__global__ __launch_bounds__(256)
void init_kernel(const float* __restrict__ W, unsigned short* __restrict__ Wt,
                 int* __restrict__ counts) {
    const int idx = blockIdx.x * 256 + threadIdx.x;
    if (idx < N_NODES) counts[idx] = 0;
    if (idx < 256 * 256) {
        const int n = idx >> 8;
        const int k = idx & 255;
        Wt[n * 256 + k] = f2bf(W[k * 256 + n]);
    }
}

// ---------------------------------------------------------------------------
// FUSED heterogeneous kernel: bid%3==0 -> GEMM block (1563 of them),
// else -> bucket-fill block (3125). The two workloads are data-independent.
// Rationale (round-3 counters): bucket_fill alone = 270 us at 0.3% VALUBusy —
// pure returning-atomic latency, zero execution-resource use. GEMM blocks
// stall on barriers/LDS. Co-residency lets the atomic latency hide under
// MFMA/VALU work: time ~ max(gemm, bucket) instead of sum, and the scan/fill
// chain + 5 launches disappear.
// ---------------------------------------------------------------------------
__global__ __launch_bounds__(256, 3)
void gemm_bucket_kernel(const float* __restrict__ A,
                        const unsigned short* __restrict__ Wt,
                        float* __restrict__ out,
                        unsigned short* __restrict__ ftb,
                        const int* __restrict__ src,
                        const int* __restrict__ dst,
                        const float* __restrict__ val,
                        int* __restrict__ counts,
                        unsigned int* __restrict__ recs)
{
    __shared__ unsigned short As[BM * BK];   // 4 KB
    __shared__ unsigned short Bs[BN * BK];   // 16 KB

    const int bid = blockIdx.x;

    if (bid % 3 != 0) {
        // ---------------- bucket-fill block ----------------
        // block ids 2*(bid/3) + (bid%3) - 1 cover 0..3124 exactly for grid 4688
        const int ebid = 2 * (bid / 3) + (bid % 3) - 1;
        const int e0 = (ebid * 256 + threadIdx.x) * 4;
        const int4   s = *(const int4*)(src + e0);
        const int4   d = *(const int4*)(dst + e0);
        const float4 v = *(const float4*)(val + e0);
        const int r0 = atomicAdd(&counts[d.x], 1);
        const int r1 = atomicAdd(&counts[d.y], 1);
        const int r2 = atomicAdd(&counts[d.z], 1);
        const int r3 = atomicAdd(&counts[d.w], 1);
        if (r0 < MAX_DEG) recs[d.x * MAX_DEG + r0] = pack_rec(s.x, v.x);
        if (r1 < MAX_DEG) recs[d.y * MAX_DEG + r1] = pack_rec(s.y, v.y);
        if (r2 < MAX_DEG) recs[d.z * MAX_DEG + r2] = pack_rec(s.z, v.z);
        if (r3 < MAX_DEG) recs[d.w * MAX_DEG + r3] = pack_rec(s.w, v.w);
        return;
    }

    // ---------------- GEMM block ----------------
    const int tid   = threadIdx.x;
    const int lane  = tid & 63;
    const int wave  = tid >> 6;
    const int waveM = wave >> 1;             // 0..1 : 32-row half
    const int waveN = wave & 1;              // 0..1 : 128-col half
    const int rowBase = (bid / 3) * BM;

    f32x4 acc[2][8];
#pragma unroll
    for (int i = 0; i < 2; i++)
#pragma unroll
        for (int j = 0; j < 8; j++) acc[i][j] = (f32x4)0.0f;

    const int sr = tid >> 2;        // 0..63
    const int sk = (tid & 3) * 8;   // 0,8,16,24
    const int quad = lane >> 4;
    const int l16  = lane & 15;

    for (int kt = 0; kt < 8; kt++) {
        const int k0 = kt * BK;
        // A tile: 64 rows x 32 cols, fp32 -> bf16 convert
        {
            const int grow = rowBase + sr;
            short8 av;
            if (grow < N_NODES) {
                const float4* pa = (const float4*)(A + (size_t)grow * 256 + k0 + sk);
                float4 f0 = pa[0];
                float4 f1 = pa[1];
                av[0] = (short)f2bf(f0.x); av[1] = (short)f2bf(f0.y);
                av[2] = (short)f2bf(f0.z); av[3] = (short)f2bf(f0.w);
                av[4] = (short)f2bf(f1.x); av[5] = (short)f2bf(f1.y);
                av[6] = (short)f2bf(f1.z); av[7] = (short)f2bf(f1.w);
            } else {
                av = (short8)0;
            }
            *(short8*)(&As[sr * BK + sk]) = av;
        }
        // B tile: 256 rows (output cols) x 32
#pragma unroll
        for (int p = 0; p < 4; p++) {
            const int r = p * 64 + sr;
            const uint4 wv = *(const uint4*)(Wt + (size_t)r * 256 + k0 + sk);
            *(uint4*)(&Bs[r * BK + sk]) = wv;
        }
        __syncthreads();

        short8 af[2], bfr[8];
#pragma unroll
        for (int i = 0; i < 2; i++)
            af[i] = *(const short8*)(&As[(waveM * 32 + i * 16 + l16) * BK + quad * 8]);
#pragma unroll
        for (int j = 0; j < 8; j++)
            bfr[j] = *(const short8*)(&Bs[(waveN * 128 + j * 16 + l16) * BK + quad * 8]);
#pragma unroll
        for (int i = 0; i < 2; i++)
#pragma unroll
            for (int j = 0; j < 8; j++)
                acc[i][j] = __builtin_amdgcn_mfma_f32_16x16x32_bf16(
                    bfr[j], af[i], acc[i][j], 0, 0, 0);   // swapped -> C^T fragment
        __syncthreads();
    }

    // Epilogue: lane holds out[row][col..col+3], row = ..+l16, col = ..+quad*4
#pragma unroll
    for (int i = 0; i < 2; i++) {
        const int row = rowBase + waveM * 32 + i * 16 + l16;
        if (row < N_NODES) {
#pragma unroll
            for (int j = 0; j < 8; j++) {
                const int col = waveN * 128 + j * 16 + quad * 4;
                f32x4 v = acc[i][j];
                *(f32x4*)(out + (size_t)row * 512 + col) = v;
                unsigned int p0 = ((unsigned int)f2bf(v[1]) << 16) | f2bf(v[0]);
                unsigned int p1 = ((unsigned int)f2bf(v[3]) << 16) | f2bf(v[2]);
                *(uint2*)(ftb + (size_t)row * 256 + col) = make_uint2(p0, p1);
            }
        }
    }
}

// ---------------------------------------------------------------------------
// Gather: one wave per dst node. out[n, 256:512] = sum_e val_e * ftb[src_e]
// Fixed-stride bucket row (len = counts[n], base = n*MAX_DEG). 8-edge unroll +
// record prefetch. At the random-access ceiling (rounds 0-2) — unchanged.
// ---------------------------------------------------------------------------
__global__ __launch_bounds__(256)
void gather_kernel(const int* __restrict__ counts,
                   const unsigned int* __restrict__ recs,
                   const unsigned short* __restrict__ ftb,
                   float* __restrict__ out)
{
    const int n = blockIdx.x * 4 + (threadIdx.x >> 6);
    if (n >= N_NODES) return;
    const int lane = threadIdx.x & 63;

    int len = counts[n];
    if (len > MAX_DEG) len = MAX_DEG;
    const unsigned int* rp = recs + (size_t)n * MAX_DEG;

    float ax = 0.f, ay = 0.f, az = 0.f, aw = 0.f;

    int e = 0;

    if (e + 7 < len) {
        unsigned int r[8];
#pragma unroll
        for (int q = 0; q < 8; q++) r[q] = rp[e + q];
        while (true) {
            const int en = e + 8;
            const bool moreN = (en + 7 < len);
            unsigned int rn[8];
            if (moreN) {
#pragma unroll
                for (int q = 0; q < 8; q++) rn[q] = rp[en + q];
            }
            ushort4 u[8];
#pragma unroll
            for (int q = 0; q < 8; q++)
                u[q] = *(const ushort4*)(ftb + (size_t)rec_src(r[q]) * 256 + lane * 4);
#pragma unroll
            for (int q = 0; q < 8; q++) {
                const float v = rec_val(r[q]);
                ax += v * bf2f(u[q].x); ay += v * bf2f(u[q].y);
                az += v * bf2f(u[q].z); aw += v * bf2f(u[q].w);
            }
            e = en;
            if (!moreN) break;
#pragma unroll
            for (int q = 0; q < 8; q++) r[q] = rn[q];
        }
    }

    for (; e + 3 < len; e += 4) {
        unsigned int r0 = rp[e];
        unsigned int r1 = rp[e + 1];
        unsigned int r2 = rp[e + 2];
        unsigned int r3 = rp[e + 3];
        ushort4 u0 = *(const ushort4*)(ftb + (size_t)rec_src(r0) * 256 + lane * 4);
        ushort4 u1 = *(const ushort4*)(ftb + (size_t)rec_src(r1) * 256 + lane * 4);
        ushort4 u2 = *(const ushort4*)(ftb + (size_t)rec_src(r2) * 256 + lane * 4);
        ushort4 u3 = *(const ushort4*)(ftb + (size_t)rec_src(r3) * 256 + lane * 4);
        const float v0 = rec_val(r0);
        const float v1 = rec_val(r1);
        const float v2 = rec_val(r2);
        const float v3 = rec_val(r3);
        ax += v0 * bf2f(u0.x); ay += v0 * bf2f(u0.y);
        az += v0 * bf2f(u0.z); aw += v0 * bf2f(u0.w);
        ax += v1 * bf2f(u1.x); ay += v1 * bf2f(u1.y);
        az += v1 * bf2f(u1.z); aw += v1 * bf2f(u1.w);
        ax += v2 * bf2f(u2.x); ay += v2 * bf2f(u2.y);
        az += v2 * bf2f(u2.z); aw += v2 * bf2f(u2.w);
        ax += v3 * bf2f(u3.x); ay += v3 * bf2f(u3.y);
        az += v3 * bf2f(u3.z); aw += v3 * bf2f(u3.w);
    }
    for (; e < len; e++) {
        unsigned int r0 = rp[e];
        ushort4 u0 = *(const ushort4*)(ftb + (size_t)rec_src(r0) * 256 + lane * 4);
        const float v0 = rec_val(r0);
        ax += v0 * bf2f(u0.x); ay += v0 * bf2f(u0.y);
        az += v0 * bf2f(u0.z); aw += v0 * bf2f(u0.w);
    }

    float4 res = make_float4(ax, ay, az, aw);
    *(float4*)(out + (size_t)n * 512 + 256 + lane * 4) = res;
}

// ---------------------------------------------------------------------------
extern "C" void kernel_launch(void* const* d_in, const int* in_sizes, int n_in,
                              void* d_out, int out_size, void* d_ws, size_t ws_size,
                              hipStream_t stream)
{
    const float* input = (const float*)d_in[0];
    const int*   esrc  = (const int*)d_in[1];
    const int*   edst  = (const int*)d_in[2];
    const float* eval  = (const float*)d_in[3];
    const float* W     = (const float*)d_in[4];
    float* out = (float*)d_out;

    char* ws = (char*)d_ws;
    unsigned short* Wt  = (unsigned short*)(ws);                 // 131072 B
    int* counts         = (int*)(ws + 131072);                   // 400000 B
    unsigned int* recs  = (unsigned int*)(ws + 532480);          // 32.0 MB (100000*80*4)
    unsigned short* ftb = (unsigned short*)(ws + 32532480);      // 51.2 MB
    // total: 83.73 MB

    init_kernel<<<INIT_NB, 256, 0, stream>>>(W, Wt, counts);

    gemm_bucket_kernel<<<FUSED_NB, 256, 0, stream>>>(
        input, Wt, out, ftb, esrc, edst, eval, counts, recs);

    gather_kernel<<<(N_NODES + 3) / 4, 256, 0, stream>>>(counts, recs, ftb, out);
}